// Round 10
// baseline (308.591 us; speedup 1.0000x reference)
//
#include <hip/hip_runtime.h>
#include <math.h>

#define MF 16384
#define HALF 8192

__device__ __forceinline__ float2 cmul(float2 a, float2 b){ return make_float2(a.x*b.x - a.y*b.y, a.x*b.y + a.y*b.x); }
__device__ __forceinline__ float2 cmulc(float2 a, float2 b){ return make_float2(a.x*b.x + a.y*b.y, a.y*b.x - a.x*b.y); } // a*conj(b)
__device__ __forceinline__ int rho4(int v){ return ((v & 3) << 2) | (v >> 2); }
__device__ __forceinline__ int sob(int k){  // slot of bin
    return (rho4(k & 15) << 10) | (rho4((k >> 4) & 15) << 6) | (rho4((k >> 8) & 15) << 2) | (k >> 12);
}
// physical LDS slot swizzle (bits0-3 xor from bits4-7; ph(s+(r<<10)) == ph(s)+(r<<10))
__device__ __forceinline__ int ph(int e){ return e ^ ((e >> 4) & 3) ^ (((e >> 6) & 3) << 2); }

__device__ __forceinline__ void bf4f(float2&a,float2&b,float2&c,float2&d){
    float t0x=a.x+c.x, t0y=a.y+c.y, t2x=a.x-c.x, t2y=a.y-c.y;
    float t1x=b.x+d.x, t1y=b.y+d.y, t3x=b.x-d.x, t3y=b.y-d.y;
    a=make_float2(t0x+t1x,t0y+t1y);
    b=make_float2(t2x+t3y,t2y-t3x);
    c=make_float2(t0x-t1x,t0y-t1y);
    d=make_float2(t2x-t3y,t2y+t3x);
}
__device__ __forceinline__ void bf4i(float2&a,float2&b,float2&c,float2&d){
    float t0x=a.x+c.x, t0y=a.y+c.y, t2x=a.x-c.x, t2y=a.y-c.y;
    float t1x=b.x+d.x, t1y=b.y+d.y, t3x=b.x-d.x, t3y=b.y-d.y;
    a=make_float2(t0x+t1x,t0y+t1y);
    b=make_float2(t2x-t3y,t2y+t3x);
    c=make_float2(t0x-t1x,t0y-t1y);
    d=make_float2(t2x+t3y,t2y-t3x);
}

#define W16_1 make_float2(0.92387953251128674f, -0.38268343236508978f)
#define W16_2 make_float2(0.70710678118654752f, -0.70710678118654752f)
#define W16_3 make_float2(0.38268343236508978f, -0.92387953251128674f)
#define W16_6 make_float2(-0.70710678118654752f, -0.70710678118654752f)
#define W16_9 make_float2(-0.92387953251128674f, 0.38268343236508978f)

__device__ __forceinline__ void dft16_fwd(float2* x){
    bf4f(x[0],x[4],x[8],x[12]);
    bf4f(x[1],x[5],x[9],x[13]);
    bf4f(x[2],x[6],x[10],x[14]);
    bf4f(x[3],x[7],x[11],x[15]);
    x[5]=cmul(x[5],W16_1);  x[9]=cmul(x[9],W16_2);   x[13]=cmul(x[13],W16_3);
    x[6]=cmul(x[6],W16_2);  { float2 t=x[10]; x[10]=make_float2(t.y,-t.x); } x[14]=cmul(x[14],W16_6);
    x[7]=cmul(x[7],W16_3);  x[11]=cmul(x[11],W16_6); x[15]=cmul(x[15],W16_9);
    bf4f(x[0],x[1],x[2],x[3]);
    bf4f(x[4],x[5],x[6],x[7]);
    bf4f(x[8],x[9],x[10],x[11]);
    bf4f(x[12],x[13],x[14],x[15]);
}
__device__ __forceinline__ void dft16_inv(float2* x){
    bf4i(x[0],x[1],x[2],x[3]);
    bf4i(x[4],x[5],x[6],x[7]);
    bf4i(x[8],x[9],x[10],x[11]);
    bf4i(x[12],x[13],x[14],x[15]);
    x[5]=cmulc(x[5],W16_1); x[9]=cmulc(x[9],W16_2);  x[13]=cmulc(x[13],W16_3);
    x[6]=cmulc(x[6],W16_2); { float2 t=x[10]; x[10]=make_float2(-t.y,t.x); } x[14]=cmulc(x[14],W16_6);
    x[7]=cmulc(x[7],W16_3); x[11]=cmulc(x[11],W16_6); x[15]=cmulc(x[15],W16_9);
    bf4i(x[0],x[4],x[8],x[12]);
    bf4i(x[1],x[5],x[9],x[13]);
    bf4i(x[2],x[6],x[10],x[14]);
    bf4i(x[3],x[7],x[11],x[15]);
}

// apply x[j] *= (or *=conj) w1^rho4(j)  -- pass0 only (one read + register powers)
template<bool INV>
__device__ __forceinline__ void tw0_apply(float2* x, float2 w1){
    float2 w2=cmul(w1,w1), w4=cmul(w2,w2), w8=cmul(w4,w4);
    float2 w3=cmul(w2,w1), w5=cmul(w4,w1), w6=cmul(w4,w2), w7=cmul(w4,w3);
    float2 w9=cmul(w8,w1), w10=cmul(w8,w2), w11=cmul(w8,w3), w12=cmul(w8,w4);
    float2 w13=cmul(w8,w5), w14=cmul(w8,w6), w15=cmul(w8,w7);
    if (!INV){
        x[1]=cmul(x[1],w4);   x[2]=cmul(x[2],w8);   x[3]=cmul(x[3],w12);
        x[4]=cmul(x[4],w1);   x[5]=cmul(x[5],w5);   x[6]=cmul(x[6],w9);
        x[7]=cmul(x[7],w13);  x[8]=cmul(x[8],w2);   x[9]=cmul(x[9],w6);
        x[10]=cmul(x[10],w10);x[11]=cmul(x[11],w14);x[12]=cmul(x[12],w3);
        x[13]=cmul(x[13],w7); x[14]=cmul(x[14],w11);x[15]=cmul(x[15],w15);
    } else {
        x[1]=cmulc(x[1],w4);   x[2]=cmulc(x[2],w8);   x[3]=cmulc(x[3],w12);
        x[4]=cmulc(x[4],w1);   x[5]=cmulc(x[5],w5);   x[6]=cmulc(x[6],w9);
        x[7]=cmulc(x[7],w13);  x[8]=cmulc(x[8],w2);   x[9]=cmulc(x[9],w6);
        x[10]=cmulc(x[10],w10);x[11]=cmulc(x[11],w14);x[12]=cmulc(x[12],w3);
        x[13]=cmulc(x[13],w7); x[14]=cmulc(x[14],w11);x[15]=cmulc(x[15],w15);
    }
}

// ---- standalone pass0 (prep only): stride-1024, LDS in/out ----
template<bool INV>
__device__ __forceinline__ void pass0(float2* A, float2 w1g, int tid){
    float2 x[16];
    int base = ph(tid);
    #pragma unroll
    for(int m=0;m<16;++m) x[m] = A[base + (m<<10)];
    if(!INV){ dft16_fwd(x); tw0_apply<false>(x, w1g); }
    else { tw0_apply<true>(x, w1g); dft16_inv(x); }
    #pragma unroll
    for(int m=0;m<16;++m) A[base + (m<<10)] = x[m];
}

// ---- pass 1: stride-64; twiddles from LDS table tw1s[(j<<6)+i1] (broadcast reads) ----
template<bool INV>
__device__ __forceinline__ void pass1(float2* A, const float2* tw1s, int tid){
    float2 x[16];
    int i1 = tid & 63;
    int B = (tid >> 6) << 10;
    int i1x = i1 ^ ((i1 >> 4) & 3);
    int b0 = B | i1x;
    int b1 = B | 64 | (i1x ^ 4);
    int b2 = B | 128 | (i1x ^ 8);
    int b3 = B | 192 | (i1x ^ 12);
    x[0]=A[b0];     x[1]=A[b1];     x[2]=A[b2];     x[3]=A[b3];
    x[4]=A[b0+256]; x[5]=A[b1+256]; x[6]=A[b2+256]; x[7]=A[b3+256];
    x[8]=A[b0+512]; x[9]=A[b1+512]; x[10]=A[b2+512];x[11]=A[b3+512];
    x[12]=A[b0+768];x[13]=A[b1+768];x[14]=A[b2+768];x[15]=A[b3+768];
    if(!INV){
        dft16_fwd(x);
        #pragma unroll
        for(int j=1;j<16;++j) x[j] = cmul(x[j], tw1s[(j<<6)+i1]);
    } else {
        #pragma unroll
        for(int j=1;j<16;++j) x[j] = cmulc(x[j], tw1s[(j<<6)+i1]);
        dft16_inv(x);
    }
    A[b0]=x[0];     A[b1]=x[1];     A[b2]=x[2];     A[b3]=x[3];
    A[b0+256]=x[4]; A[b1+256]=x[5]; A[b2+256]=x[6]; A[b3+256]=x[7];
    A[b0+512]=x[8]; A[b1+512]=x[9]; A[b2+512]=x[10];A[b3+512]=x[11];
    A[b0+768]=x[12];A[b1+768]=x[13];A[b2+768]=x[14];A[b3+768]=x[15];
}

// ---- pass 2: stride-4; twiddles from LDS table tw2s[(j<<2)+j2] (broadcast reads) ----
template<bool INV>
__device__ __forceinline__ void pass2(float2* A, const float2* tw2s, int tid){
    float2 x[16];
    int q = tid >> 2, j2 = tid & 3;
    int qb = q << 6, qa = q & 3;
    int c0 = qb | (j2 ^ 0);
    int c1 = qb | 16 | (j2 ^ 1);
    int c2 = qb | 32 | (j2 ^ 2);
    int c3 = qb | 48 | (j2 ^ 3);
    int r0 = (qa ^ 0) << 2, r1 = (qa ^ 1) << 2, r2 = (qa ^ 2) << 2, r3 = (qa ^ 3) << 2;
    x[0]=A[c0+r0];  x[1]=A[c0+r1];  x[2]=A[c0+r2];  x[3]=A[c0+r3];
    x[4]=A[c1+r0];  x[5]=A[c1+r1];  x[6]=A[c1+r2];  x[7]=A[c1+r3];
    x[8]=A[c2+r0];  x[9]=A[c2+r1];  x[10]=A[c2+r2]; x[11]=A[c2+r3];
    x[12]=A[c3+r0]; x[13]=A[c3+r1]; x[14]=A[c3+r2]; x[15]=A[c3+r3];
    if(!INV){
        dft16_fwd(x);
        #pragma unroll
        for(int j=1;j<16;++j) x[j] = cmul(x[j], tw2s[(j<<2)+j2]);
    } else {
        #pragma unroll
        for(int j=1;j<16;++j) x[j] = cmulc(x[j], tw2s[(j<<2)+j2]);
        dft16_inv(x);
    }
    A[c0+r0]=x[0];  A[c0+r1]=x[1];  A[c0+r2]=x[2];  A[c0+r3]=x[3];
    A[c1+r0]=x[4];  A[c1+r1]=x[5];  A[c1+r2]=x[6];  A[c1+r3]=x[7];
    A[c2+r0]=x[8];  A[c2+r1]=x[9];  A[c2+r2]=x[10]; A[c2+r3]=x[11];
    A[c3+r0]=x[12]; A[c3+r1]=x[13]; A[c3+r2]=x[14]; A[c3+r3]=x[15];
}

// ---- pass 3: final radix-4 ----
template<bool INV>
__device__ __forceinline__ void pass3(float2* A, int tid){
    int sgm = ((tid>>2)&3) ^ (((tid>>4)&3)<<2);
    #pragma unroll
    for(int rr=0; rr<4; ++rr){
        int base = (tid<<2) | (rr<<12);
        float2 a=A[(base|0)^sgm], b=A[(base|1)^sgm], c=A[(base|2)^sgm], d=A[(base|3)^sgm];
        if(!INV) bf4f(a,b,c,d); else bf4i(a,b,c,d);
        A[(base|0)^sgm]=a; A[(base|1)^sgm]=b; A[(base|2)^sgm]=c; A[(base|3)^sgm]=d;
    }
}

// ---------------- eval (+table init in extra block) ----------------
__global__ __launch_bounds__(1024) void k_evalinit(const float2* __restrict__ Lam, const float2* __restrict__ P,
        const float2* __restrict__ Bc, const float2* __restrict__ C,
        const float* __restrict__ log_step, float2* __restrict__ E,
        float2* __restrict__ baseg, float2* __restrict__ tw1g, float2* __restrict__ tw2g) {
    __shared__ float2 bTs[16][64];
    __shared__ float2 pTs[16][64];
    __shared__ float2 S10s[16], S11s[16];
    __shared__ float2 C_l[64][65];
    __shared__ float2 tile[16][65];
    int tid = threadIdx.x;
    if (blockIdx.x >= 256){
        const double TP = 6.2831853071795864769;
        double a = -TP * (double)tid / 16384.0;
        baseg[tid] = make_float2((float)cos(a), (float)sin(a));
        double a1 = -TP * (double)((tid & 63) * rho4(tid >> 6)) / 1024.0;
        tw1g[tid] = make_float2((float)cos(a1), (float)sin(a1));
        if (tid < 64){
            double a2 = -TP * (double)((tid & 3) * rho4(tid >> 2)) / 64.0;
            tw2g[tid] = make_float2((float)cos(a2), (float)sin(a2));
        }
        return;
    }
    int l0 = blockIdx.x * 64;
    float step = expf(log_step[0]);
    {
        int dq = tid >> 6, n = tid & 63;
        #pragma unroll
        for (int p = 0; p < 4; ++p) { int dd = dq + p * 16; C_l[n][dd] = C[dd * 64 + n]; }
    }
    __syncthreads();
    int w = tid >> 6;
    int lane = tid & 63;
    for (int p = 0; p < 4; ++p) {
        int l = l0 + p * 16 + w;
        float lf = (float)l * (1.0f / 16384.0f);
        float s2 = sinpif(lf), c2 = cospif(lf);
        float2 q1 = make_float2(2.0f*c2*c2, -2.0f*s2*c2);   // 1+Om
        {
            int n = lane;
            float2 q2 = make_float2(4.0f*s2*s2, 4.0f*s2*c2); // 2(1-Om)
            float2 ln = Lam[n];
            float2 lq = cmul(ln, q1);
            float2 den = make_float2(q2.x - step*lq.x, q2.y - step*lq.y);
            float idn = step / (den.x*den.x + den.y*den.y);
            float2 T = make_float2(den.x*idn, -den.y*idn);
            float2 bn = Bc[n], pn = P[n];
            float2 bT = cmul(bn, T), pT = cmul(pn, T);
            bTs[w][n] = bT; pTs[w][n] = pT;
            float2 s10 = make_float2(pn.x*bT.x + pn.y*bT.y, pn.x*bT.y - pn.y*bT.x);
            float2 s11 = make_float2(pn.x*pT.x + pn.y*pT.y, pn.x*pT.y - pn.y*pT.x);
            #pragma unroll
            for (int off = 32; off > 0; off >>= 1) {
                s10.x += __shfl_xor(s10.x, off);
                s10.y += __shfl_xor(s10.y, off);
                s11.x += __shfl_xor(s11.x, off);
                s11.y += __shfl_xor(s11.y, off);
            }
            if (n == 0) { S10s[w] = s10; S11s[w] = s11; }
        }
        __syncthreads();
        {
            int d = lane;
            float2 S00 = make_float2(0.f, 0.f), S01 = make_float2(0.f, 0.f);
            #pragma unroll 8
            for (int n = 0; n < 64; ++n) {
                float2 cn = C_l[n][d];
                float2 bT = bTs[w][n];
                float2 pT = pTs[w][n];
                S00.x += cn.x*bT.x + cn.y*bT.y;  S00.y += cn.x*bT.y - cn.y*bT.x;
                S01.x += cn.x*pT.x + cn.y*pT.y;  S01.y += cn.x*pT.y - cn.y*pT.x;
            }
            float2 S10 = S10s[w], S11 = S11s[w];
            float2 k11 = cmul(q1, S11); k11.x += 1.0f;
            float2 k10q = cmul(q1, S10);
            float ik = 1.0f / (k11.x*k11.x + k11.y*k11.y);
            float2 quo = make_float2((k10q.x*k11.x + k10q.y*k11.y) * ik,
                                     (k10q.y*k11.x - k10q.x*k11.y) * ik);
            float2 corr = cmul(S01, quo);
            tile[w][d] = make_float2(2.0f*(S00.x - corr.x), 2.0f*(S00.y - corr.y));
        }
        __syncthreads();
        {
            int lo = tid & 15, dq = tid >> 4;
            E[(size_t)dq * MF + l0 + p * 16 + lo] = tile[lo][dq];
        }
        __syncthreads();
    }
}

// ---------------- mid: prep (blocks 0..63) || transpose_in (blocks 64..1087) ----------------
union MidShm {
    struct { float2 A[MF]; float2 tw1s[1024]; float2 tw2s[64]; } p;
    float t[256][65];
};

__global__ __launch_bounds__(1024, 4)
__attribute__((amdgpu_waves_per_eu(4, 4)))
void k_mid(const float2* __restrict__ E, float4* __restrict__ Ktab,
        const float2* __restrict__ baseg, const float2* __restrict__ tw1g, const float2* __restrict__ tw2g,
        const float* __restrict__ u, float* __restrict__ uT) {
    __shared__ MidShm sh;
    int tid = threadIdx.x;
    if (blockIdx.x >= 64){
        int cid = blockIdx.x - 64;
        int b = cid >> 6, t0c = (cid & 63) << 8;
        const float* ub = u + ((size_t)(b * MF + t0c)) * 64;
        #pragma unroll
        for (int it = 0; it < 16; ++it){
            int tl = it * 16 + (tid >> 6), dl = tid & 63;
            sh.t[tl][dl] = ub[(size_t)tl * 64 + dl];
        }
        __syncthreads();
        float* dst = uT + (size_t)b * 64 * MF + t0c;
        #pragma unroll
        for (int it = 0; it < 16; ++it){
            int dd = (tid >> 8) + it * 4, tl = tid & 255;
            dst[(size_t)dd * MF + tl] = sh.t[tl][dd];
        }
        return;
    }
    float2* A = sh.p.A;
    float2* tw1s = sh.p.tw1s;
    float2* tw2s = sh.p.tw2s;
    float2 w1g = baseg[tid];
    tw1s[tid] = tw1g[tid];
    if (tid < 64) tw2s[tid] = tw2g[tid];
    int d = blockIdx.x;
    const float2* Ed = E + (size_t)d * MF;
    #pragma unroll
    for (int r = 0; r < 16; ++r) { int l = tid + (r << 10); A[ph(sob(l))] = Ed[l]; }
    __syncthreads();
    pass3<true>(A, tid); __syncthreads();
    pass2<true>(A, tw2s, tid); __syncthreads();
    pass1<true>(A, tw1s, tid); __syncthreads();
    pass0<true>(A, w1g, tid); __syncthreads();
    const float s = 1.0f / (float)MF;
    float2 rv[8];
    #pragma unroll
    for (int r = 0; r < 8; ++r) {
        int t = tid + (r << 10);
        rv[r] = make_float2(A[ph(2*t)].x * s, A[ph(2*t+1)].x * s);
    }
    __syncthreads();
    int pht = ph(tid);
    #pragma unroll
    for (int r = 0; r < 16; ++r) A[pht + (r << 10)] = (r < 8) ? rv[r] : make_float2(0.f, 0.f);
    __syncthreads();
    pass0<false>(A, w1g, tid); __syncthreads();
    pass1<false>(A, tw1s, tid); __syncthreads();
    pass2<false>(A, tw2s, tid); __syncthreads();
    pass3<false>(A, tid); __syncthreads();
    float4* Kd = Ktab + (size_t)d * MF;
    int Cbits = (rho4(tid >> 6) << 4) | (rho4((tid >> 2) & 15) << 8) | ((tid & 3) << 12);
    const float ksc = 1.0f / (float)MF;
    #pragma unroll
    for (int r = 0; r < 16; ++r) {
        int k = Cbits | rho4(r);
        int kp = (MF - k) & (MF - 1);
        int p = sob(kp);
        float kf = (float)k * (1.0f / 16384.0f);
        float2 w = make_float2(cospif(kf), -sinpif(kf));
        float2 Zk = A[pht + (r << 10)];
        float2 Zm = A[ph(p)]; Zm.y = -Zm.y;
        float2 Ue = make_float2(0.5f*(Zk.x + Zm.x), 0.5f*(Zk.y + Zm.y));
        float2 dd = make_float2(Zk.x - Zm.x, Zk.y - Zm.y);
        float2 Uo = make_float2(0.5f*dd.y, -0.5f*dd.x);
        float2 t2 = cmul(w, Uo);
        Kd[tid + (r << 10)] = make_float4((Ue.x + t2.x)*ksc, (Ue.y + t2.y)*ksc,
                                          (Ue.x - t2.x)*ksc, (Ue.y - t2.y)*ksc);
    }
}

// ---------------- main conv: fused-load P0, table P1/P2, split kd prefetch, register IP0 store ----------------
template<bool TRANS>
__global__ __launch_bounds__(1024, 4)
__attribute__((amdgpu_waves_per_eu(4, 4)))
void k_conv(const float* __restrict__ u, const float* __restrict__ uT,
        const float4* __restrict__ Ktab, const float* __restrict__ Dp,
        float* __restrict__ yT, float* __restrict__ yout,
        const float2* __restrict__ baseg, const float2* __restrict__ tw1g, const float2* __restrict__ tw2g) {
    __shared__ float2 A[MF];
    __shared__ float2 tw1s[1024];
    __shared__ float2 tw2s[64];
    int tid = threadIdx.x;
    float2 w1g = baseg[tid];
    tw1s[tid] = tw1g[tid];
    if (tid < 64) tw2s[tid] = tw2g[tid];
    int bid = blockIdx.x;
    int vb = ((bid & 7) << 7) | (bid >> 3);
    int d = vb >> 4, b = vb & 15;
    int bd = (b << 6) | d;
    int base = ph(tid);
    const float2* src = (const float2*)(uT + (size_t)bd * MF);
    const float* ub = u + ((size_t)b * MF) * 64 + d;
    // --- P0 with fused global load (zero-padded upper half) ---
    {
        float2 x[16];
        #pragma unroll
        for (int m = 0; m < 16; ++m){
            if (m < 8){
                if (TRANS) x[m] = src[tid + (m << 10)];
                else { int t = tid + (m << 10); x[m] = make_float2(ub[(size_t)(2*t)*64], ub[(size_t)(2*t+1)*64]); }
            } else x[m] = make_float2(0.f, 0.f);
        }
        dft16_fwd(x);
        tw0_apply<false>(x, w1g);
        #pragma unroll
        for (int m = 0; m < 16; ++m) A[base + (m << 10)] = x[m];
    }
    __syncthreads();
    pass1<false>(A, tw1s, tid); __syncthreads();
    pass2<false>(A, tw2s, tid); __syncthreads();
    // first-half Ktab prefetch before pass3 (latency hidden under it)
    const float4* Kd = Ktab + (size_t)d * MF;
    float4 kd[8];
    #pragma unroll
    for (int r = 0; r < 8; ++r) kd[r] = Kd[tid + (r << 10)];
    pass3<false>(A, tid); __syncthreads();
    // pointwise: second-half prefetch issued first (L2-hit, hidden under first-half compute)
    float4 kd2[8];
    #pragma unroll
    for (int r = 0; r < 8; ++r) kd2[r] = Kd[tid + ((r + 8) << 10)];
    int Cbits = (rho4(tid >> 6) << 4) | (rho4((tid >> 2) & 15) << 8) | ((tid & 3) << 12);
    float2 Wr[16];
    #pragma unroll
    for (int r = 0; r < 16; ++r) {
        int k = Cbits | rho4(r);
        int kp = (MF - k) & (MF - 1);
        int p = sob(kp);
        float kf = (float)k * (1.0f / 16384.0f);
        float2 w = make_float2(cospif(kf), -sinpif(kf));
        float2 Zk = A[base + (r << 10)];
        float2 Zm = A[ph(p)]; Zm.y = -Zm.y;
        float2 Ue = make_float2(0.5f*(Zk.x + Zm.x), 0.5f*(Zk.y + Zm.y));
        float2 dd = make_float2(Zk.x - Zm.x, Zk.y - Zm.y);
        float2 Uo = make_float2(0.5f*dd.y, -0.5f*dd.x);
        float2 t2 = cmul(w, Uo);
        float2 X0 = make_float2(Ue.x + t2.x, Ue.y + t2.y);
        float2 X1 = make_float2(Ue.x - t2.x, Ue.y - t2.y);
        float4 kr = (r < 8) ? kd[r & 7] : kd2[r & 7];
        float2 Y0 = cmul(X0, make_float2(kr.x, kr.y));
        float2 Y1 = cmul(X1, make_float2(kr.z, kr.w));
        float2 Ey = make_float2(0.5f*(Y0.x + Y1.x), 0.5f*(Y0.y + Y1.y));
        float2 Dy = make_float2(Y0.x - Y1.x, Y0.y - Y1.y);
        float2 Oy = cmulc(Dy, w);
        Oy.x *= 0.5f; Oy.y *= 0.5f;
        Wr[r] = make_float2(Ey.x - Oy.y, Ey.y + Oy.x);   // Z' = Ey + i*Oy
    }
    __syncthreads();
    #pragma unroll
    for (int r = 0; r < 16; ++r) A[base + (r << 10)] = Wr[r];
    __syncthreads();
    pass3<true>(A, tid); __syncthreads();
    pass2<true>(A, tw2s, tid); __syncthreads();
    pass1<true>(A, tw1s, tid); __syncthreads();
    // --- IP0 in registers + direct store (D*u handled in k_out for TRANS path) ---
    {
        float2 x[16];
        #pragma unroll
        for (int m = 0; m < 16; ++m) x[m] = A[base + (m << 10)];
        tw0_apply<true>(x, w1g);
        dft16_inv(x);
        if (TRANS){
            float2* dst = (float2*)(yT + (size_t)bd * MF);
            #pragma unroll
            for (int m = 0; m < 8; ++m) dst[tid + (m << 10)] = x[m];
        } else {
            float Dd = Dp[d];
            float* yb = yout + ((size_t)b * MF) * 64 + d;
            #pragma unroll
            for (int m = 0; m < 8; ++m){
                int t = tid + (m << 10);
                yb[(size_t)(2*t)*64]   = x[m].x + Dd * ub[(size_t)(2*t)*64];
                yb[(size_t)(2*t+1)*64] = x[m].y + Dd * ub[(size_t)(2*t+1)*64];
            }
        }
    }
}

// ---------------- output: y[b][t][d] = yT[b][d][t] + D[d]*u[b][t][d] ----------------
__global__ void k_out(const float* __restrict__ yT, const float* __restrict__ u,
                      const float* __restrict__ Dp, float* __restrict__ y) {
    __shared__ float tile[64][65];
    int b = blockIdx.y, t0 = blockIdx.x * 64, tid = threadIdx.x;
    #pragma unroll
    for (int k2 = 0; k2 < 16; ++k2) {
        int idx = tid + k2 * 256;
        int dl = idx >> 6, tl = idx & 63;
        tile[dl][tl] = yT[((size_t)b * 64 + dl) * MF + t0 + tl];
    }
    __syncthreads();
    #pragma unroll
    for (int k2 = 0; k2 < 16; ++k2) {
        int idx = tid + k2 * 256;
        int tl = idx >> 6, dl = idx & 63;
        size_t gi = ((size_t)(b * MF + t0 + tl)) * 64 + dl;
        y[gi] = tile[dl][tl] + Dp[dl] * u[gi];
    }
}

extern "C" void kernel_launch(void* const* d_in, const int* in_sizes, int n_in,
                              void* d_out, int out_size, void* d_ws, size_t ws_size,
                              hipStream_t stream) {
    const float*  u   = (const float*)d_in[0];
    const float2* Lam = (const float2*)d_in[1];
    const float2* P   = (const float2*)d_in[2];
    const float2* Bc  = (const float2*)d_in[3];
    const float2* C   = (const float2*)d_in[4];
    const float*  Dp  = (const float*)d_in[5];
    const float*  ls  = (const float*)d_in[6];
    float* y = (float*)d_out;
    char* ws = (char*)d_ws;

    size_t off = 0;
    float2* baseg = (float2*)(ws + off); off += (size_t)1024 * sizeof(float2);        // 8 KB
    float2* tw1g  = (float2*)(ws + off); off += (size_t)1024 * sizeof(float2);        // 8 KB
    float2* tw2g  = (float2*)(ws + off); off += (size_t)64 * sizeof(float2) + 512;    // 1 KB
    float2* E     = (float2*)(ws + off); off += (size_t)64 * MF * sizeof(float2);     // 8 MB
    float4* Ktab  = (float4*)(ws + off); off += (size_t)64 * MF * sizeof(float4);     // 16 MB
    float*  uT    = (float*) (ws + off); off += (size_t)1024 * MF * sizeof(float);    // 64 MB
    float*  yT    = (float*) (ws + off); off += (size_t)1024 * MF * sizeof(float);    // 64 MB
    bool trans = (ws_size >= off);

    k_evalinit<<<257, 1024, 0, stream>>>(Lam, P, Bc, C, ls, E, baseg, tw1g, tw2g);
    k_mid<<<trans ? 1088 : 64, 1024, 0, stream>>>(E, Ktab, baseg, tw1g, tw2g, u, uT);

    if (trans) {
        k_conv<true><<<1024, 1024, 0, stream>>>(u, uT, Ktab, Dp, yT, y, baseg, tw1g, tw2g);
        k_out<<<dim3(MF / 64, 16), 256, 0, stream>>>(yT, u, Dp, y);
    } else {
        k_conv<false><<<1024, 1024, 0, stream>>>(u, nullptr, Ktab, Dp, nullptr, y, baseg, tw1g, tw2g);
    }
}

// Round 11
// 293.172 us; speedup vs baseline: 1.0526x; 1.0526x over previous
//
#include <hip/hip_runtime.h>
#include <math.h>

#define MF 16384
#define HALF 8192

__device__ __forceinline__ float2 cmul(float2 a, float2 b){ return make_float2(a.x*b.x - a.y*b.y, a.x*b.y + a.y*b.x); }
__device__ __forceinline__ float2 cmulc(float2 a, float2 b){ return make_float2(a.x*b.x + a.y*b.y, a.y*b.x - a.x*b.y); } // a*conj(b)
__device__ __forceinline__ int rho4(int v){ return ((v & 3) << 2) | (v >> 2); }
__device__ __forceinline__ int sob(int k){  // slot of bin
    return (rho4(k & 15) << 10) | (rho4((k >> 4) & 15) << 6) | (rho4((k >> 8) & 15) << 2) | (k >> 12);
}
// physical LDS slot swizzle (bits0-3 xor from bits4-7; ph(s+(r<<10)) == ph(s)+(r<<10))
__device__ __forceinline__ int ph(int e){ return e ^ ((e >> 4) & 3) ^ (((e >> 6) & 3) << 2); }

__device__ __forceinline__ void bf4f(float2&a,float2&b,float2&c,float2&d){
    float t0x=a.x+c.x, t0y=a.y+c.y, t2x=a.x-c.x, t2y=a.y-c.y;
    float t1x=b.x+d.x, t1y=b.y+d.y, t3x=b.x-d.x, t3y=b.y-d.y;
    a=make_float2(t0x+t1x,t0y+t1y);
    b=make_float2(t2x+t3y,t2y-t3x);
    c=make_float2(t0x-t1x,t0y-t1y);
    d=make_float2(t2x-t3y,t2y+t3x);
}
__device__ __forceinline__ void bf4i(float2&a,float2&b,float2&c,float2&d){
    float t0x=a.x+c.x, t0y=a.y+c.y, t2x=a.x-c.x, t2y=a.y-c.y;
    float t1x=b.x+d.x, t1y=b.y+d.y, t3x=b.x-d.x, t3y=b.y-d.y;
    a=make_float2(t0x+t1x,t0y+t1y);
    b=make_float2(t2x-t3y,t2y+t3x);
    c=make_float2(t0x-t1x,t0y-t1y);
    d=make_float2(t2x+t3y,t2y-t3x);
}

#define W16_1 make_float2(0.92387953251128674f, -0.38268343236508978f)
#define W16_2 make_float2(0.70710678118654752f, -0.70710678118654752f)
#define W16_3 make_float2(0.38268343236508978f, -0.92387953251128674f)
#define W16_6 make_float2(-0.70710678118654752f, -0.70710678118654752f)
#define W16_9 make_float2(-0.92387953251128674f, 0.38268343236508978f)

__device__ __forceinline__ void dft16_fwd(float2* x){
    bf4f(x[0],x[4],x[8],x[12]);
    bf4f(x[1],x[5],x[9],x[13]);
    bf4f(x[2],x[6],x[10],x[14]);
    bf4f(x[3],x[7],x[11],x[15]);
    x[5]=cmul(x[5],W16_1);  x[9]=cmul(x[9],W16_2);   x[13]=cmul(x[13],W16_3);
    x[6]=cmul(x[6],W16_2);  { float2 t=x[10]; x[10]=make_float2(t.y,-t.x); } x[14]=cmul(x[14],W16_6);
    x[7]=cmul(x[7],W16_3);  x[11]=cmul(x[11],W16_6); x[15]=cmul(x[15],W16_9);
    bf4f(x[0],x[1],x[2],x[3]);
    bf4f(x[4],x[5],x[6],x[7]);
    bf4f(x[8],x[9],x[10],x[11]);
    bf4f(x[12],x[13],x[14],x[15]);
}
__device__ __forceinline__ void dft16_inv(float2* x){
    bf4i(x[0],x[1],x[2],x[3]);
    bf4i(x[4],x[5],x[6],x[7]);
    bf4i(x[8],x[9],x[10],x[11]);
    bf4i(x[12],x[13],x[14],x[15]);
    x[5]=cmulc(x[5],W16_1); x[9]=cmulc(x[9],W16_2);  x[13]=cmulc(x[13],W16_3);
    x[6]=cmulc(x[6],W16_2); { float2 t=x[10]; x[10]=make_float2(-t.y,t.x); } x[14]=cmulc(x[14],W16_6);
    x[7]=cmulc(x[7],W16_3); x[11]=cmulc(x[11],W16_6); x[15]=cmulc(x[15],W16_9);
    bf4i(x[0],x[4],x[8],x[12]);
    bf4i(x[1],x[5],x[9],x[13]);
    bf4i(x[2],x[6],x[10],x[14]);
    bf4i(x[3],x[7],x[11],x[15]);
}

// apply x[m] *= (or *=conj) w1^e(m), e(m) = 4*(m&3) + (m>>2).
// Rolling evaluation: only {w1,w4,wrow,wc} live (8 VGPR) instead of 15 powers (30 VGPR).
template<bool INV>
__device__ __forceinline__ void tw0_apply(float2* x, float2 w1){
    float2 w4;
    { float2 w2 = cmul(w1,w1); w4 = cmul(w2,w2); }
    // row 0: exponents 4,8,12 on x[1..3]
    {
        float2 wc = w4;
        if(!INV) x[1]=cmul(x[1],wc); else x[1]=cmulc(x[1],wc);
        wc = cmul(wc,w4);
        if(!INV) x[2]=cmul(x[2],wc); else x[2]=cmulc(x[2],wc);
        wc = cmul(wc,w4);
        if(!INV) x[3]=cmul(x[3],wc); else x[3]=cmulc(x[3],wc);
    }
    // rows 1..3: exponent row + 4c on x[4*row+c]
    float2 wrow = w1;
    #pragma unroll
    for(int row=1; row<4; ++row){
        float2 wc = wrow;
        #pragma unroll
        for(int c=0;c<4;++c){
            int m = 4*row + c;
            if(!INV) x[m]=cmul(x[m],wc); else x[m]=cmulc(x[m],wc);
            if (c < 3) wc = cmul(wc,w4);
        }
        if (row < 3) wrow = cmul(wrow,w1);
    }
}

// ---- standalone pass0 (prep only): stride-1024, LDS in/out ----
template<bool INV>
__device__ __forceinline__ void pass0(float2* A, float2 w1g, int tid){
    float2 x[16];
    int base = ph(tid);
    #pragma unroll
    for(int m=0;m<16;++m) x[m] = A[base + (m<<10)];
    if(!INV){ dft16_fwd(x); tw0_apply<false>(x, w1g); }
    else { tw0_apply<true>(x, w1g); dft16_inv(x); }
    #pragma unroll
    for(int m=0;m<16;++m) A[base + (m<<10)] = x[m];
}

// ---- pass 1: stride-64; twiddles from LDS table tw1s[(j<<6)+i1] (broadcast reads) ----
template<bool INV>
__device__ __forceinline__ void pass1(float2* A, const float2* tw1s, int tid){
    float2 x[16];
    int i1 = tid & 63;
    int B = (tid >> 6) << 10;
    int i1x = i1 ^ ((i1 >> 4) & 3);
    int b0 = B | i1x;
    int b1 = B | 64 | (i1x ^ 4);
    int b2 = B | 128 | (i1x ^ 8);
    int b3 = B | 192 | (i1x ^ 12);
    x[0]=A[b0];     x[1]=A[b1];     x[2]=A[b2];     x[3]=A[b3];
    x[4]=A[b0+256]; x[5]=A[b1+256]; x[6]=A[b2+256]; x[7]=A[b3+256];
    x[8]=A[b0+512]; x[9]=A[b1+512]; x[10]=A[b2+512];x[11]=A[b3+512];
    x[12]=A[b0+768];x[13]=A[b1+768];x[14]=A[b2+768];x[15]=A[b3+768];
    if(!INV){
        dft16_fwd(x);
        #pragma unroll
        for(int j=1;j<16;++j) x[j] = cmul(x[j], tw1s[(j<<6)+i1]);
    } else {
        #pragma unroll
        for(int j=1;j<16;++j) x[j] = cmulc(x[j], tw1s[(j<<6)+i1]);
        dft16_inv(x);
    }
    A[b0]=x[0];     A[b1]=x[1];     A[b2]=x[2];     A[b3]=x[3];
    A[b0+256]=x[4]; A[b1+256]=x[5]; A[b2+256]=x[6]; A[b3+256]=x[7];
    A[b0+512]=x[8]; A[b1+512]=x[9]; A[b2+512]=x[10];A[b3+512]=x[11];
    A[b0+768]=x[12];A[b1+768]=x[13];A[b2+768]=x[14];A[b3+768]=x[15];
}

// ---- pass 2: stride-4; twiddles from LDS table tw2s[(j<<2)+j2] (broadcast reads) ----
template<bool INV>
__device__ __forceinline__ void pass2(float2* A, const float2* tw2s, int tid){
    float2 x[16];
    int q = tid >> 2, j2 = tid & 3;
    int qb = q << 6, qa = q & 3;
    int c0 = qb | (j2 ^ 0);
    int c1 = qb | 16 | (j2 ^ 1);
    int c2 = qb | 32 | (j2 ^ 2);
    int c3 = qb | 48 | (j2 ^ 3);
    int r0 = (qa ^ 0) << 2, r1 = (qa ^ 1) << 2, r2 = (qa ^ 2) << 2, r3 = (qa ^ 3) << 2;
    x[0]=A[c0+r0];  x[1]=A[c0+r1];  x[2]=A[c0+r2];  x[3]=A[c0+r3];
    x[4]=A[c1+r0];  x[5]=A[c1+r1];  x[6]=A[c1+r2];  x[7]=A[c1+r3];
    x[8]=A[c2+r0];  x[9]=A[c2+r1];  x[10]=A[c2+r2]; x[11]=A[c2+r3];
    x[12]=A[c3+r0]; x[13]=A[c3+r1]; x[14]=A[c3+r2]; x[15]=A[c3+r3];
    if(!INV){
        dft16_fwd(x);
        #pragma unroll
        for(int j=1;j<16;++j) x[j] = cmul(x[j], tw2s[(j<<2)+j2]);
    } else {
        #pragma unroll
        for(int j=1;j<16;++j) x[j] = cmulc(x[j], tw2s[(j<<2)+j2]);
        dft16_inv(x);
    }
    A[c0+r0]=x[0];  A[c0+r1]=x[1];  A[c0+r2]=x[2];  A[c0+r3]=x[3];
    A[c1+r0]=x[4];  A[c1+r1]=x[5];  A[c1+r2]=x[6];  A[c1+r3]=x[7];
    A[c2+r0]=x[8];  A[c2+r1]=x[9];  A[c2+r2]=x[10]; A[c2+r3]=x[11];
    A[c3+r0]=x[12]; A[c3+r1]=x[13]; A[c3+r2]=x[14]; A[c3+r3]=x[15];
}

// ---- pass 3: final radix-4 ----
template<bool INV>
__device__ __forceinline__ void pass3(float2* A, int tid){
    int sgm = ((tid>>2)&3) ^ (((tid>>4)&3)<<2);
    #pragma unroll
    for(int rr=0; rr<4; ++rr){
        int base = (tid<<2) | (rr<<12);
        float2 a=A[(base|0)^sgm], b=A[(base|1)^sgm], c=A[(base|2)^sgm], d=A[(base|3)^sgm];
        if(!INV) bf4f(a,b,c,d); else bf4i(a,b,c,d);
        A[(base|0)^sgm]=a; A[(base|1)^sgm]=b; A[(base|2)^sgm]=c; A[(base|3)^sgm]=d;
    }
}

// ---- pointwise for one chunk R (compile-time): unpack, multiply by Kd, repack ----
template<int R>
__device__ __forceinline__ float2 pw_compute(const float2* A, const float4* Kd,
                                             int tid, int base, int Cbits){
    constexpr int RR = ((R & 3) << 2) | (R >> 2);   // rho4(R)
    int k = Cbits | RR;
    int kp = (MF - k) & (MF - 1);
    int p = sob(kp);
    float kf = (float)k * (1.0f / 16384.0f);
    float2 w = make_float2(cospif(kf), -sinpif(kf));
    float2 Zk = A[base + (R << 10)];
    float2 Zm = A[ph(p)]; Zm.y = -Zm.y;
    float4 kr = Kd[tid + (R << 10)];
    float2 Ue = make_float2(0.5f*(Zk.x + Zm.x), 0.5f*(Zk.y + Zm.y));
    float2 dd = make_float2(Zk.x - Zm.x, Zk.y - Zm.y);
    float2 Uo = make_float2(0.5f*dd.y, -0.5f*dd.x);
    float2 t2 = cmul(w, Uo);
    float2 X0 = make_float2(Ue.x + t2.x, Ue.y + t2.y);
    float2 X1 = make_float2(Ue.x - t2.x, Ue.y - t2.y);
    float2 Y0 = cmul(X0, make_float2(kr.x, kr.y));
    float2 Y1 = cmul(X1, make_float2(kr.z, kr.w));
    float2 Ey = make_float2(0.5f*(Y0.x + Y1.x), 0.5f*(Y0.y + Y1.y));
    float2 Dy = make_float2(Y0.x - Y1.x, Y0.y - Y1.y);
    float2 Oy = cmulc(Dy, w);
    return make_float2(Ey.x - 0.5f*Oy.y, Ey.y + 0.5f*Oy.x);   // Z' = Ey + i*Oy/... (verified r4)
}

// ---------------- eval (+table init in extra block) ----------------
__global__ __launch_bounds__(1024) void k_evalinit(const float2* __restrict__ Lam, const float2* __restrict__ P,
        const float2* __restrict__ Bc, const float2* __restrict__ C,
        const float* __restrict__ log_step, float2* __restrict__ E,
        float2* __restrict__ baseg, float2* __restrict__ tw1g, float2* __restrict__ tw2g) {
    __shared__ float2 bTs[16][64];
    __shared__ float2 pTs[16][64];
    __shared__ float2 S10s[16], S11s[16];
    __shared__ float2 C_l[64][65];
    __shared__ float2 tile[16][65];
    int tid = threadIdx.x;
    if (blockIdx.x >= 256){
        const double TP = 6.2831853071795864769;
        double a = -TP * (double)tid / 16384.0;
        baseg[tid] = make_float2((float)cos(a), (float)sin(a));
        double a1 = -TP * (double)((tid & 63) * rho4(tid >> 6)) / 1024.0;
        tw1g[tid] = make_float2((float)cos(a1), (float)sin(a1));
        if (tid < 64){
            double a2 = -TP * (double)((tid & 3) * rho4(tid >> 2)) / 64.0;
            tw2g[tid] = make_float2((float)cos(a2), (float)sin(a2));
        }
        return;
    }
    int l0 = blockIdx.x * 64;
    float step = expf(log_step[0]);
    {
        int dq = tid >> 6, n = tid & 63;
        #pragma unroll
        for (int p = 0; p < 4; ++p) { int dd = dq + p * 16; C_l[n][dd] = C[dd * 64 + n]; }
    }
    __syncthreads();
    int w = tid >> 6;
    int lane = tid & 63;
    for (int p = 0; p < 4; ++p) {
        int l = l0 + p * 16 + w;
        float lf = (float)l * (1.0f / 16384.0f);
        float s2 = sinpif(lf), c2 = cospif(lf);
        float2 q1 = make_float2(2.0f*c2*c2, -2.0f*s2*c2);   // 1+Om
        {
            int n = lane;
            float2 q2 = make_float2(4.0f*s2*s2, 4.0f*s2*c2); // 2(1-Om)
            float2 ln = Lam[n];
            float2 lq = cmul(ln, q1);
            float2 den = make_float2(q2.x - step*lq.x, q2.y - step*lq.y);
            float idn = step / (den.x*den.x + den.y*den.y);
            float2 T = make_float2(den.x*idn, -den.y*idn);
            float2 bn = Bc[n], pn = P[n];
            float2 bT = cmul(bn, T), pT = cmul(pn, T);
            bTs[w][n] = bT; pTs[w][n] = pT;
            float2 s10 = make_float2(pn.x*bT.x + pn.y*bT.y, pn.x*bT.y - pn.y*bT.x);
            float2 s11 = make_float2(pn.x*pT.x + pn.y*pT.y, pn.x*pT.y - pn.y*pT.x);
            #pragma unroll
            for (int off = 32; off > 0; off >>= 1) {
                s10.x += __shfl_xor(s10.x, off);
                s10.y += __shfl_xor(s10.y, off);
                s11.x += __shfl_xor(s11.x, off);
                s11.y += __shfl_xor(s11.y, off);
            }
            if (n == 0) { S10s[w] = s10; S11s[w] = s11; }
        }
        __syncthreads();
        {
            int d = lane;
            float2 S00 = make_float2(0.f, 0.f), S01 = make_float2(0.f, 0.f);
            #pragma unroll 8
            for (int n = 0; n < 64; ++n) {
                float2 cn = C_l[n][d];
                float2 bT = bTs[w][n];
                float2 pT = pTs[w][n];
                S00.x += cn.x*bT.x + cn.y*bT.y;  S00.y += cn.x*bT.y - cn.y*bT.x;
                S01.x += cn.x*pT.x + cn.y*pT.y;  S01.y += cn.x*pT.y - cn.y*pT.x;
            }
            float2 S10 = S10s[w], S11 = S11s[w];
            float2 k11 = cmul(q1, S11); k11.x += 1.0f;
            float2 k10q = cmul(q1, S10);
            float ik = 1.0f / (k11.x*k11.x + k11.y*k11.y);
            float2 quo = make_float2((k10q.x*k11.x + k10q.y*k11.y) * ik,
                                     (k10q.y*k11.x - k10q.x*k11.y) * ik);
            float2 corr = cmul(S01, quo);
            tile[w][d] = make_float2(2.0f*(S00.x - corr.x), 2.0f*(S00.y - corr.y));
        }
        __syncthreads();
        {
            int lo = tid & 15, dq = tid >> 4;
            E[(size_t)dq * MF + l0 + p * 16 + lo] = tile[lo][dq];
        }
        __syncthreads();
    }
}

// ---------------- mid: prep (blocks 0..63) || transpose_in (blocks 64..1087) ----------------
union MidShm {
    struct { float2 A[MF]; float2 tw1s[1024]; float2 tw2s[64]; } p;
    float t[256][65];
};

__global__ __launch_bounds__(1024)
void k_mid(const float2* __restrict__ E, float4* __restrict__ Ktab,
        const float2* __restrict__ baseg, const float2* __restrict__ tw1g, const float2* __restrict__ tw2g,
        const float* __restrict__ u, float* __restrict__ uT) {
    __shared__ MidShm sh;
    int tid = threadIdx.x;
    if (blockIdx.x >= 64){
        int cid = blockIdx.x - 64;
        int b = cid >> 6, t0c = (cid & 63) << 8;
        const float* ub = u + ((size_t)(b * MF + t0c)) * 64;
        #pragma unroll
        for (int it = 0; it < 16; ++it){
            int tl = it * 16 + (tid >> 6), dl = tid & 63;
            sh.t[tl][dl] = ub[(size_t)tl * 64 + dl];
        }
        __syncthreads();
        float* dst = uT + (size_t)b * 64 * MF + t0c;
        #pragma unroll
        for (int it = 0; it < 16; ++it){
            int dd = (tid >> 8) + it * 4, tl = tid & 255;
            dst[(size_t)dd * MF + tl] = sh.t[tl][dd];
        }
        return;
    }
    float2* A = sh.p.A;
    float2* tw1s = sh.p.tw1s;
    float2* tw2s = sh.p.tw2s;
    float2 w1g = baseg[tid];
    tw1s[tid] = tw1g[tid];
    if (tid < 64) tw2s[tid] = tw2g[tid];
    int d = blockIdx.x;
    const float2* Ed = E + (size_t)d * MF;
    #pragma unroll
    for (int r = 0; r < 16; ++r) { int l = tid + (r << 10); A[ph(sob(l))] = Ed[l]; }
    __syncthreads();
    pass3<true>(A, tid); __syncthreads();
    pass2<true>(A, tw2s, tid); __syncthreads();
    pass1<true>(A, tw1s, tid); __syncthreads();
    pass0<true>(A, w1g, tid); __syncthreads();
    const float s = 1.0f / (float)MF;
    float2 rv[8];
    #pragma unroll
    for (int r = 0; r < 8; ++r) {
        int t = tid + (r << 10);
        rv[r] = make_float2(A[ph(2*t)].x * s, A[ph(2*t+1)].x * s);
    }
    __syncthreads();
    int pht = ph(tid);
    #pragma unroll
    for (int r = 0; r < 16; ++r) A[pht + (r << 10)] = (r < 8) ? rv[r] : make_float2(0.f, 0.f);
    __syncthreads();
    pass0<false>(A, w1g, tid); __syncthreads();
    pass1<false>(A, tw1s, tid); __syncthreads();
    pass2<false>(A, tw2s, tid); __syncthreads();
    pass3<false>(A, tid); __syncthreads();
    float4* Kd = Ktab + (size_t)d * MF;
    int Cbits = (rho4(tid >> 6) << 4) | (rho4((tid >> 2) & 15) << 8) | ((tid & 3) << 12);
    const float ksc = 1.0f / (float)MF;
    #pragma unroll
    for (int r = 0; r < 16; ++r) {
        int k = Cbits | rho4(r);
        int kp = (MF - k) & (MF - 1);
        int p = sob(kp);
        float kf = (float)k * (1.0f / 16384.0f);
        float2 w = make_float2(cospif(kf), -sinpif(kf));
        float2 Zk = A[pht + (r << 10)];
        float2 Zm = A[ph(p)]; Zm.y = -Zm.y;
        float2 Ue = make_float2(0.5f*(Zk.x + Zm.x), 0.5f*(Zk.y + Zm.y));
        float2 dd = make_float2(Zk.x - Zm.x, Zk.y - Zm.y);
        float2 Uo = make_float2(0.5f*dd.y, -0.5f*dd.x);
        float2 t2 = cmul(w, Uo);
        Kd[tid + (r << 10)] = make_float4((Ue.x + t2.x)*ksc, (Ue.y + t2.y)*ksc,
                                          (Ue.x - t2.x)*ksc, (Ue.y - t2.y)*ksc);
    }
}

// ---------------- main conv: fused-load P0, table P1/P2, grouped PW (low pressure), register IP0 store ----------------
template<bool TRANS>
__global__ __launch_bounds__(1024)
void k_conv(const float* __restrict__ u, const float* __restrict__ uT,
        const float4* __restrict__ Ktab, const float* __restrict__ Dp,
        float* __restrict__ yT, float* __restrict__ yout,
        const float2* __restrict__ baseg, const float2* __restrict__ tw1g, const float2* __restrict__ tw2g) {
    __shared__ float2 A[MF];
    __shared__ float2 tw1s[1024];
    __shared__ float2 tw2s[64];
    int tid = threadIdx.x;
    float2 w1g = baseg[tid];
    tw1s[tid] = tw1g[tid];
    if (tid < 64) tw2s[tid] = tw2g[tid];
    int bid = blockIdx.x;
    int vb = ((bid & 7) << 7) | (bid >> 3);
    int d = vb >> 4, b = vb & 15;
    int bd = (b << 6) | d;
    int base = ph(tid);
    const float2* src = (const float2*)(uT + (size_t)bd * MF);
    const float* ub = u + ((size_t)b * MF) * 64 + d;
    // --- P0 with fused global load (zero-padded upper half) ---
    {
        float2 x[16];
        #pragma unroll
        for (int m = 0; m < 16; ++m){
            if (m < 8){
                if (TRANS) x[m] = src[tid + (m << 10)];
                else { int t = tid + (m << 10); x[m] = make_float2(ub[(size_t)(2*t)*64], ub[(size_t)(2*t+1)*64]); }
            } else x[m] = make_float2(0.f, 0.f);
        }
        dft16_fwd(x);
        tw0_apply<false>(x, w1g);
        #pragma unroll
        for (int m = 0; m < 16; ++m) A[base + (m << 10)] = x[m];
    }
    __syncthreads();
    pass1<false>(A, tw1s, tid); __syncthreads();
    pass2<false>(A, tw2s, tid); __syncthreads();
    pass3<false>(A, tid); __syncthreads();
    // --- PW in conjugate-closed chunk groups (peak live ~45 VGPR, no spills) ---
    // partner chunk of chunk r = rho4((16 - rho4(r)) & 15):
    // pairs (0,0),(2,2),(1,3),(9,10),(4,15),(5,14),(6,13),(7,12),(8,11)
    {
        const float4* Kd = Ktab + (size_t)d * MF;
        int Cbits = (rho4(tid >> 6) << 4) | (rho4((tid >> 2) & 15) << 8) | ((tid & 3) << 12);
        {   // G1: {0,2}
            float2 wa = pw_compute<0>(A, Kd, tid, base, Cbits);
            float2 wb = pw_compute<2>(A, Kd, tid, base, Cbits);
            __syncthreads();
            A[base + (0<<10)] = wa; A[base + (2<<10)] = wb;
        }
        {   // G2: {1,3} U {9,10}
            float2 wa = pw_compute<1>(A, Kd, tid, base, Cbits);
            float2 wb = pw_compute<3>(A, Kd, tid, base, Cbits);
            float2 wc = pw_compute<9>(A, Kd, tid, base, Cbits);
            float2 wd = pw_compute<10>(A, Kd, tid, base, Cbits);
            __syncthreads();
            A[base + (1<<10)] = wa; A[base + (3<<10)] = wb;
            A[base + (9<<10)] = wc; A[base + (10<<10)] = wd;
        }
        {   // G3: {4,15} U {5,14}
            float2 wa = pw_compute<4>(A, Kd, tid, base, Cbits);
            float2 wb = pw_compute<15>(A, Kd, tid, base, Cbits);
            float2 wc = pw_compute<5>(A, Kd, tid, base, Cbits);
            float2 wd = pw_compute<14>(A, Kd, tid, base, Cbits);
            __syncthreads();
            A[base + (4<<10)] = wa; A[base + (15<<10)] = wb;
            A[base + (5<<10)] = wc; A[base + (14<<10)] = wd;
        }
        {   // G4: {6,13} U {7,12}
            float2 wa = pw_compute<6>(A, Kd, tid, base, Cbits);
            float2 wb = pw_compute<13>(A, Kd, tid, base, Cbits);
            float2 wc = pw_compute<7>(A, Kd, tid, base, Cbits);
            float2 wd = pw_compute<12>(A, Kd, tid, base, Cbits);
            __syncthreads();
            A[base + (6<<10)] = wa; A[base + (13<<10)] = wb;
            A[base + (7<<10)] = wc; A[base + (12<<10)] = wd;
        }
        {   // G5: {8,11}
            float2 wa = pw_compute<8>(A, Kd, tid, base, Cbits);
            float2 wb = pw_compute<11>(A, Kd, tid, base, Cbits);
            __syncthreads();
            A[base + (8<<10)] = wa; A[base + (11<<10)] = wb;
        }
    }
    __syncthreads();
    pass3<true>(A, tid); __syncthreads();
    pass2<true>(A, tw2s, tid); __syncthreads();
    pass1<true>(A, tw1s, tid); __syncthreads();
    // --- IP0 in registers + direct store (D*u handled in k_out for TRANS path) ---
    {
        float2 x[16];
        #pragma unroll
        for (int m = 0; m < 16; ++m) x[m] = A[base + (m << 10)];
        tw0_apply<true>(x, w1g);
        dft16_inv(x);
        if (TRANS){
            float2* dst = (float2*)(yT + (size_t)bd * MF);
            #pragma unroll
            for (int m = 0; m < 8; ++m) dst[tid + (m << 10)] = x[m];
        } else {
            float Dd = Dp[d];
            float* yb = yout + ((size_t)b * MF) * 64 + d;
            #pragma unroll
            for (int m = 0; m < 8; ++m){
                int t = tid + (m << 10);
                yb[(size_t)(2*t)*64]   = x[m].x + Dd * ub[(size_t)(2*t)*64];
                yb[(size_t)(2*t+1)*64] = x[m].y + Dd * ub[(size_t)(2*t+1)*64];
            }
        }
    }
}

// ---------------- output: y[b][t][d] = yT[b][d][t] + D[d]*u[b][t][d] ----------------
__global__ void k_out(const float* __restrict__ yT, const float* __restrict__ u,
                      const float* __restrict__ Dp, float* __restrict__ y) {
    __shared__ float tile[64][65];
    int b = blockIdx.y, t0 = blockIdx.x * 64, tid = threadIdx.x;
    #pragma unroll
    for (int k2 = 0; k2 < 16; ++k2) {
        int idx = tid + k2 * 256;
        int dl = idx >> 6, tl = idx & 63;
        tile[dl][tl] = yT[((size_t)b * 64 + dl) * MF + t0 + tl];
    }
    __syncthreads();
    #pragma unroll
    for (int k2 = 0; k2 < 16; ++k2) {
        int idx = tid + k2 * 256;
        int tl = idx >> 6, dl = idx & 63;
        size_t gi = ((size_t)(b * MF + t0 + tl)) * 64 + dl;
        y[gi] = tile[dl][tl] + Dp[dl] * u[gi];
    }
}

extern "C" void kernel_launch(void* const* d_in, const int* in_sizes, int n_in,
                              void* d_out, int out_size, void* d_ws, size_t ws_size,
                              hipStream_t stream) {
    const float*  u   = (const float*)d_in[0];
    const float2* Lam = (const float2*)d_in[1];
    const float2* P   = (const float2*)d_in[2];
    const float2* Bc  = (const float2*)d_in[3];
    const float2* C   = (const float2*)d_in[4];
    const float*  Dp  = (const float*)d_in[5];
    const float*  ls  = (const float*)d_in[6];
    float* y = (float*)d_out;
    char* ws = (char*)d_ws;

    size_t off = 0;
    float2* baseg = (float2*)(ws + off); off += (size_t)1024 * sizeof(float2);        // 8 KB
    float2* tw1g  = (float2*)(ws + off); off += (size_t)1024 * sizeof(float2);        // 8 KB
    float2* tw2g  = (float2*)(ws + off); off += (size_t)64 * sizeof(float2) + 512;    // 1 KB
    float2* E     = (float2*)(ws + off); off += (size_t)64 * MF * sizeof(float2);     // 8 MB
    float4* Ktab  = (float4*)(ws + off); off += (size_t)64 * MF * sizeof(float4);     // 16 MB
    float*  uT    = (float*) (ws + off); off += (size_t)1024 * MF * sizeof(float);    // 64 MB
    float*  yT    = (float*) (ws + off); off += (size_t)1024 * MF * sizeof(float);    // 64 MB
    bool trans = (ws_size >= off);

    k_evalinit<<<257, 1024, 0, stream>>>(Lam, P, Bc, C, ls, E, baseg, tw1g, tw2g);
    k_mid<<<trans ? 1088 : 64, 1024, 0, stream>>>(E, Ktab, baseg, tw1g, tw2g, u, uT);

    if (trans) {
        k_conv<true><<<1024, 1024, 0, stream>>>(u, uT, Ktab, Dp, yT, y, baseg, tw1g, tw2g);
        k_out<<<dim3(MF / 64, 16), 256, 0, stream>>>(yT, u, Dp, y);
    } else {
        k_conv<false><<<1024, 1024, 0, stream>>>(u, nullptr, Ktab, Dp, nullptr, y, baseg, tw1g, tw2g);
    }
}